// Round 1
// baseline (142.078 us; speedup 1.0000x reference)
//
#include <hip/hip_runtime.h>
#include <hip/hip_bf16.h>

#define B_TOT 16384
#define OBS 64
#define ACT 8
#define H 128
#define NNODE 5
#define HEADS 2
#define TB 16
#define ROWS (TB*NNODE)   // 80 rows per block

typedef __attribute__((ext_vector_type(8))) short short8;
typedef __attribute__((ext_vector_type(4))) short short4v;
typedef __attribute__((ext_vector_type(4))) float f32x4;

__device__ __forceinline__ float bf2f(short s){
  unsigned int u = ((unsigned int)(unsigned short)s) << 16;
  return __uint_as_float(u);
}
__device__ __forceinline__ short f2bf(float f){
  __hip_bfloat16 h = __float2bfloat16(f);
  return *reinterpret_cast<short*>(&h);
}

// LDS arena (bytes). X/h1 region is reused for Wh after GEMM2.
#define LDS_X     0        // [80][64]  bf16 swz  (10240 B)
#define LDS_H1    10240    // [80][128] bf16 swz  (20480 B)
#define LDS_WH    0        // [80][128] bf16 swz  (aliases X+h1, dead by then)
#define LDS_EMB   30720    // [80][128] bf16 swz  (20480 B)
#define LDS_FINAL 51200    // [16][256] bf16 swz  (8192 B)
#define LDS_V1    59392    // [16][128] bf16 swz  (4096 B)
#define LDS_P1    63488    // [16][128] bf16 swz  (4096 B)
#define LDS_EI0   67584    // [16] f32
#define LDS_EJ    67648    // [80] f32
#define LDS_ATT   67968    // [80] f32
#define LDS_TOT   68352

// XOR-swizzled LDS address: row-major [.][STRIDE] bf16, byte ^= (row&7)<<4
template<int STRIDE>
__device__ __forceinline__ char* sw(char* base, int r, int k){
  int b = r*(STRIDE*2) + k*2;
  return base + (b ^ ((r & 7) << 4));
}

// weight segment offsets in d_ws (elements, bf16)
#define W_W1T  0       // [128][64]
#define W_W2T  8192    // [128][128]
#define W_GWT  24576   // [2][128][128]
#define W_VW1T 57344   // [128][256]
#define W_PW1T 90112   // [128][256]
#define W_TOTAL 122880

__global__ void prep_weights(const float* __restrict__ enc_w1, const float* __restrict__ enc_w2,
                             const float* __restrict__ gat_w, const float* __restrict__ val_w1,
                             const float* __restrict__ pol_w1, unsigned short* __restrict__ wt){
  int t = blockIdx.x * 256 + threadIdx.x;
  float v;
  if (t < 8192){                 // enc_w1t[c][k] = enc_w1[k][c], K=64
    int c = t >> 6, k = t & 63;
    v = enc_w1[k*H + c];
  } else if (t < 24576){         // enc_w2t, K=128
    int u = t - 8192; int c = u >> 7, k = u & 127;
    v = enc_w2[k*H + c];
  } else if (t < 57344){         // gat_wt[h][c][k], K=128
    int u = t - 24576; int h = u >> 14; int r = u & 16383;
    int c = r >> 7, k = r & 127;
    v = gat_w[h*16384 + k*H + c];
  } else if (t < 90112){         // val_w1t[c][k], K=256
    int u = t - 57344; int c = u >> 8, k = u & 255;
    v = val_w1[k*H + c];
  } else {                       // pol_w1t[c][k], K=256
    int u = t - 90112; int c = u >> 8, k = u & 255;
    v = pol_w1[k*H + c];
  }
  __hip_bfloat16 hv = __float2bfloat16(v);
  wt[t] = *reinterpret_cast<unsigned short*>(&hv);
}

// GEMM over the 80-row tile: A (80 x K) in LDS (stride K, swizzled), B = wt (transposed [128][K]),
// out (80 x 128) bf16 to LDS (stride 128, swizzled). Wave w owns output cols [32w, 32w+32).
template<int K, bool RELU, bool HASBIAS>
__device__ __forceinline__ void gemm80(char* lds, int a_off, const unsigned short* __restrict__ wt,
                                       const float* __restrict__ bias, int o_off, int lane, int wave){
  constexpr int KS = K / 32;
  const int lm = lane & 15;
  const int kb = (lane >> 4) * 8;
  const int c0 = wave*32 + lm;
  const int c1 = c0 + 16;
  short8 bf0[KS], bf1[KS];
  #pragma unroll
  for (int s = 0; s < KS; ++s){
    bf0[s] = *reinterpret_cast<const short8*>(wt + c0*K + s*32 + kb);
    bf1[s] = *reinterpret_cast<const short8*>(wt + c1*K + s*32 + kb);
  }
  const float bias0 = HASBIAS ? bias[c0] : 0.f;
  const float bias1 = HASBIAS ? bias[c1] : 0.f;
  #pragma unroll
  for (int mt = 0; mt < 5; ++mt){
    f32x4 acc0 = {0.f,0.f,0.f,0.f}, acc1 = {0.f,0.f,0.f,0.f};
    #pragma unroll
    for (int s = 0; s < KS; ++s){
      short8 a = *reinterpret_cast<short8*>(sw<K>(lds + a_off, mt*16 + lm, s*32 + kb));
      acc0 = __builtin_amdgcn_mfma_f32_16x16x32_bf16(a, bf0[s], acc0, 0, 0, 0);
      acc1 = __builtin_amdgcn_mfma_f32_16x16x32_bf16(a, bf1[s], acc1, 0, 0, 0);
    }
    const int r0 = mt*16 + ((lane >> 4) << 2);
    #pragma unroll
    for (int j = 0; j < 4; ++j){
      float v0 = acc0[j] + bias0;
      float v1 = acc1[j] + bias1;
      if (RELU){ v0 = fmaxf(v0, 0.f); v1 = fmaxf(v1, 0.f); }
      *reinterpret_cast<short*>(sw<H>(lds + o_off, r0 + j, c0)) = f2bf(v0);
      *reinterpret_cast<short*>(sw<H>(lds + o_off, r0 + j, c1)) = f2bf(v1);
    }
  }
}

// heads GEMM: A = final (16 x 256) in LDS, B = wt [128][256], out (16 x 128) bf16+relu to LDS
__device__ __forceinline__ void gemm16(char* lds, const unsigned short* __restrict__ wt,
                                       const float* __restrict__ bias, int o_off, int lane, int wave){
  const int lm = lane & 15;
  const int kb = (lane >> 4) * 8;
  const int c0 = wave*32 + lm;
  const int c1 = c0 + 16;
  f32x4 acc0 = {0.f,0.f,0.f,0.f}, acc1 = {0.f,0.f,0.f,0.f};
  #pragma unroll
  for (int s = 0; s < 8; ++s){
    short8 a  = *reinterpret_cast<short8*>(sw<256>(lds + LDS_FINAL, lm, s*32 + kb));
    short8 b0 = *reinterpret_cast<const short8*>(wt + c0*256 + s*32 + kb);
    short8 b1 = *reinterpret_cast<const short8*>(wt + c1*256 + s*32 + kb);
    acc0 = __builtin_amdgcn_mfma_f32_16x16x32_bf16(a, b0, acc0, 0, 0, 0);
    acc1 = __builtin_amdgcn_mfma_f32_16x16x32_bf16(a, b1, acc1, 0, 0, 0);
  }
  const int r0 = (lane >> 4) << 2;
  #pragma unroll
  for (int j = 0; j < 4; ++j){
    float v0 = fmaxf(acc0[j] + bias[c0], 0.f);
    float v1 = fmaxf(acc1[j] + bias[c1], 0.f);
    *reinterpret_cast<short*>(sw<H>(lds + o_off, r0 + j, c0)) = f2bf(v0);
    *reinterpret_cast<short*>(sw<H>(lds + o_off, r0 + j, c1)) = f2bf(v1);
  }
}

__global__ __launch_bounds__(256, 2) void colight_main(
    const float* __restrict__ obs, const float* __restrict__ nobs, const int* __restrict__ adj,
    const float* __restrict__ enc_b1, const float* __restrict__ enc_b2,
    const float* __restrict__ gat_a,
    const float* __restrict__ val_b1, const float* __restrict__ val_w2, const float* __restrict__ val_b2,
    const float* __restrict__ pol_b1, const float* __restrict__ pol_w2, const float* __restrict__ pol_b2,
    const unsigned short* __restrict__ wt_all,
    float* __restrict__ dout)
{
  __shared__ __align__(16) char lds[LDS_TOT];
  const int tid  = threadIdx.x;
  const int lane = tid & 63;
  const int wave = tid >> 6;
  const int b0   = blockIdx.x * TB;

  const unsigned short* w1t  = wt_all + W_W1T;
  const unsigned short* w2t  = wt_all + W_W2T;
  const unsigned short* gwt  = wt_all + W_GWT;
  const unsigned short* vw1t = wt_all + W_VW1T;
  const unsigned short* pw1t = wt_all + W_PW1T;

  // ---- stage X = all_obs tile (80 x 64) as bf16, swizzled ----
  #pragma unroll
  for (int i = 0; i < 5; ++i){
    int chunk = tid + i*256;          // 1280 float4-chunks
    int row = chunk >> 4;
    int c4  = (chunk & 15) * 4;
    int lb  = row / 5;
    int n   = row - lb*5;
    const float* src = (n == 0) ? (obs  + (size_t)(b0 + lb)*OBS + c4)
                                : (nobs + ((size_t)(b0 + lb)*4 + (n-1))*OBS + c4);
    float4 v = *reinterpret_cast<const float4*>(src);
    short4v p = { f2bf(v.x), f2bf(v.y), f2bf(v.z), f2bf(v.w) };
    *reinterpret_cast<short4v*>(sw<OBS>(lds + LDS_X, row, c4)) = p;
  }
  __syncthreads();

  // ---- encoder ----
  gemm80<64, true, true>(lds, LDS_X, w1t, enc_b1, LDS_H1, lane, wave);
  __syncthreads();
  gemm80<128, false, true>(lds, LDS_H1, w2t, enc_b2, LDS_EMB, lane, wave);
  __syncthreads();

  float* ei0 = reinterpret_cast<float*>(lds + LDS_EI0);
  float* ej  = reinterpret_cast<float*>(lds + LDS_EJ);
  float* att = reinterpret_cast<float*>(lds + LDS_ATT);

  // ---- GAT heads ----
  for (int h = 0; h < HEADS; ++h){
    gemm80<128, false, false>(lds, LDS_EMB, gwt + h*16384, nullptr, LDS_WH, lane, wave);
    __syncthreads();

    // dots: ej for all 80 rows (a2), ei0 for the 16 node-0 rows (a1)
    if (tid < 192){
      const int isei = (tid >= 160);
      const int q    = isei ? (tid - 160) : tid;
      const int row  = isei ? ((q >> 1) * 5) : (q >> 1);
      const int half = q & 1;
      const float* av = gat_a + h*2*H + (isei ? 0 : H);
      float s = 0.f;
      #pragma unroll
      for (int i = 0; i < 8; ++i){
        short8 v = *reinterpret_cast<short8*>(sw<H>(lds + LDS_WH, row, half*64 + i*8));
        #pragma unroll
        for (int e = 0; e < 8; ++e) s += bf2f(v[e]) * av[half*64 + i*8 + e];
      }
      s += __shfl_xor(s, 1);
      if (!half){ if (isei) ei0[q >> 1] = s; else ej[q >> 1] = s; }
    }
    __syncthreads();

    // masked softmax over the 5 neighbors (row i=0 only)
    if (tid < TB){
      const int lb = tid;
      const float e0 = ei0[lb];
      float p[NNODE]; int msk[NNODE];
      float m = -1e30f;
      #pragma unroll
      for (int j = 0; j < NNODE; ++j){
        msk[j] = adj[(size_t)(b0 + lb)*NNODE + j];
        float s = e0 + ej[lb*NNODE + j];
        s = (s > 0.f) ? s : 0.2f * s;     // leaky relu
        p[j] = s;
        if (msk[j] && s > m) m = s;
      }
      float den = 0.f;
      #pragma unroll
      for (int j = 0; j < NNODE; ++j){
        float e = msk[j] ? __expf(p[j] - m) : 0.f;
        p[j] = e; den += e;
      }
      const float inv = 1.f / den;
      #pragma unroll
      for (int j = 0; j < NNODE; ++j) att[lb*NNODE + j] = p[j] * inv;
    }
    __syncthreads();

    // combine: final[lb][h*128 + c] = sum_j att[j] * Wh[lb*5+j][c]
    {
      const int lb = tid >> 4;
      const int cg = tid & 15;
      float acc[8] = {0,0,0,0,0,0,0,0};
      #pragma unroll
      for (int j = 0; j < NNODE; ++j){
        const float aj = att[lb*NNODE + j];
        short8 v = *reinterpret_cast<short8*>(sw<H>(lds + LDS_WH, lb*NNODE + j, cg*8));
        #pragma unroll
        for (int e = 0; e < 8; ++e) acc[e] += aj * bf2f(v[e]);
      }
      short8 o;
      #pragma unroll
      for (int e = 0; e < 8; ++e) o[e] = f2bf(acc[e]);
      *reinterpret_cast<short8*>(sw<HEADS*H>(lds + LDS_FINAL, lb, h*H + cg*8)) = o;
    }
    __syncthreads();
  }

  // ---- heads: hidden layers via MFMA ----
  gemm16(lds, vw1t, val_b1, LDS_V1, lane, wave);
  gemm16(lds, pw1t, pol_b1, LDS_P1, lane, wave);
  __syncthreads();

  // ---- final projections (f32) ----
  if (tid < 128){
    const int lb = tid >> 3, a = tid & 7;
    float s = pol_b2[a];
    #pragma unroll
    for (int i = 0; i < 16; ++i){
      short8 v = *reinterpret_cast<short8*>(sw<H>(lds + LDS_P1, lb, i*8));
      #pragma unroll
      for (int e = 0; e < 8; ++e) s += bf2f(v[e]) * pol_w2[(i*8 + e)*ACT + a];
    }
    dout[B_TOT + (size_t)(b0 + lb)*ACT + a] = s;
  } else if (tid < 160){
    const int q = tid - 128;
    const int lb = q >> 1, half = q & 1;
    float s = 0.f;
    #pragma unroll
    for (int i = 0; i < 8; ++i){
      short8 v = *reinterpret_cast<short8*>(sw<H>(lds + LDS_V1, lb, half*64 + i*8));
      #pragma unroll
      for (int e = 0; e < 8; ++e) s += bf2f(v[e]) * val_w2[half*64 + i*8 + e];
    }
    s += __shfl_xor(s, 1);
    if (!half) dout[b0 + lb] = s + val_b2[0];
  }
}

extern "C" void kernel_launch(void* const* d_in, const int* in_sizes, int n_in,
                              void* d_out, int out_size, void* d_ws, size_t ws_size,
                              hipStream_t stream) {
  (void)in_sizes; (void)n_in; (void)out_size; (void)ws_size;
  const float* obs    = (const float*)d_in[0];
  const float* nobs   = (const float*)d_in[1];
  const int*   adj    = (const int*)  d_in[2];
  const float* enc_w1 = (const float*)d_in[3];
  const float* enc_b1 = (const float*)d_in[4];
  const float* enc_w2 = (const float*)d_in[5];
  const float* enc_b2 = (const float*)d_in[6];
  const float* gat_w  = (const float*)d_in[7];
  const float* gat_a  = (const float*)d_in[8];
  const float* val_w1 = (const float*)d_in[9];
  const float* val_b1 = (const float*)d_in[10];
  const float* val_w2 = (const float*)d_in[11];
  const float* val_b2 = (const float*)d_in[12];
  const float* pol_w1 = (const float*)d_in[13];
  const float* pol_b1 = (const float*)d_in[14];
  const float* pol_w2 = (const float*)d_in[15];
  const float* pol_b2 = (const float*)d_in[16];

  unsigned short* wt = (unsigned short*)d_ws;

  prep_weights<<<W_TOTAL/256, 256, 0, stream>>>(enc_w1, enc_w2, gat_w, val_w1, pol_w1, wt);

  colight_main<<<B_TOT/TB, 256, 0, stream>>>(
      obs, nobs, adj, enc_b1, enc_b2, gat_a,
      val_b1, val_w2, val_b2, pol_b1, pol_w2, pol_b2,
      wt, (float*)d_out);
}